// Round 1
// baseline (218.506 us; speedup 1.0000x reference)
//
#include <hip/hip_runtime.h>
#include <math.h>

#define TPB 256

__global__ __launch_bounds__(TPB) void geo_kernel(const float* __restrict__ coords,
                                                  float* __restrict__ out, int n) {
    __shared__ float s_ang[TPB * 3];   // 3 KB
    __shared__ float s_frm[TPB * 9];   // 9 KB

    const int tid  = threadIdx.x;
    const int base = blockIdx.x * TPB;
    const int r    = base + tid;

    if (r < n) {
        // Row used for the frame computation: rows 0 / n-1 copy rows 1 / n-2.
        int rr = r;
        if (rr < 1) rr = 1;
        if (rr > n - 2) rr = n - 2;

        const float* p = coords + 3 * (size_t)(rr - 1);
        float ax = p[0], ay = p[1], az = p[2];
        float bx = p[3], by = p[4], bz = p[5];
        float cx = p[6], cy = p[7], cz = p[8];

        float d1x = bx - ax, d1y = by - ay, d1z = bz - az;
        float d2x = cx - bx, d2y = cy - by, d2z = cz - bz;

        float n1   = sqrtf(d1x * d1x + d1y * d1y + d1z * d1z) + 1e-10f;
        float inv1 = 1.0f / n1;
        float v1x = d1x * inv1, v1y = d1y * inv1, v1z = d1z * inv1;

        float n2   = sqrtf(d2x * d2x + d2y * d2y + d2z * d2z) + 1e-10f;
        float inv2 = 1.0f / n2;
        float v2x = d2x * inv2, v2y = d2y * inv2, v2z = d2z * inv2;

        float dotv   = v1x * v2x + v1y * v2y + v1z * v2z;
        float cosang = fminf(1.0f, fmaxf(-1.0f, dotv));
        float ang    = (r == 0 || r == n - 1) ? 0.0f : acosf(cosang);

        // Gram-Schmidt: e2 = normalize(v2 - proj*v1) with proj = UNclamped dot.
        float tx = v2x - dotv * v1x, ty = v2y - dotv * v1y, tz = v2z - dotv * v1z;
        float tn   = sqrtf(tx * tx + ty * ty + tz * tz) + 1e-10f;
        float invt = 1.0f / tn;
        float e2x = tx * invt, e2y = ty * invt, e2z = tz * invt;

        // e3 = cross(e1, e2)
        float e3x = v1y * e2z - v1z * e2y;
        float e3y = v1z * e2x - v1x * e2z;
        float e3z = v1x * e2y - v1y * e2x;

        s_ang[tid * 3 + 0] = ang;
        s_ang[tid * 3 + 1] = ang;
        s_ang[tid * 3 + 2] = ang;

        float* f = s_frm + tid * 9;
        f[0] = v1x; f[1] = v1y; f[2] = v1z;
        f[3] = e2x; f[4] = e2y; f[5] = e2z;
        f[6] = e3x; f[7] = e3y; f[8] = e3z;
    }
    __syncthreads();

    float* angles = out;                        // n*3 floats
    float* frames = out + (size_t)n * 3;        // n*9 floats

    int valid = n - base;
    if (valid > TPB) valid = TPB;

    if (valid == TPB) {
        // Fully-coalesced float4 flush. Block byte offsets: angles 3072*b,
        // frames 9216*b -> both 16B aligned.
        float4*       ga = (float4*)(angles + (size_t)base * 3);
        const float4* sa = (const float4*)s_ang;
        if (tid < (TPB * 3) / 4) ga[tid] = sa[tid];   // 192 float4s

        float4*       gf = (float4*)(frames + (size_t)base * 9);
        const float4* sf = (const float4*)s_frm;
        #pragma unroll
        for (int k = 0; k < (TPB * 9) / 4; k += TPB) {  // 576 float4s
            int idx = k + tid;
            if (idx < (TPB * 9) / 4) gf[idx] = sf[idx];
        }
    } else {
        // Tail block: scalar stores.
        if (r < n) {
            angles[(size_t)r * 3 + 0] = s_ang[tid * 3 + 0];
            angles[(size_t)r * 3 + 1] = s_ang[tid * 3 + 1];
            angles[(size_t)r * 3 + 2] = s_ang[tid * 3 + 2];
            for (int k = 0; k < 9; ++k)
                frames[(size_t)r * 9 + k] = s_frm[tid * 9 + k];
        }
    }
}

extern "C" void kernel_launch(void* const* d_in, const int* in_sizes, int n_in,
                              void* d_out, int out_size, void* d_ws, size_t ws_size,
                              hipStream_t stream) {
    const float* coords = (const float*)d_in[0];
    float*       out    = (float*)d_out;
    int n = in_sizes[0] / 3;
    int blocks = (n + TPB - 1) / TPB;
    hipLaunchKernelGGL(geo_kernel, dim3(blocks), dim3(TPB), 0, stream, coords, out, n);
}